// Round 1
// 640.523 us; speedup vs baseline: 1.0817x; 1.0817x over previous
//
#include <hip/hip_runtime.h>
#include <hip/hip_bf16.h>

#define G1 __attribute__((address_space(1)))
#define L3 __attribute__((address_space(3)))

typedef __bf16 bf16x8 __attribute__((ext_vector_type(8)));
typedef _Float16 half4 __attribute__((ext_vector_type(4)));
typedef float f32x4 __attribute__((ext_vector_type(4)));

__device__ __forceinline__ ushort f2bf(float f) {
  union { float f; uint u; } v; v.f = f;
  uint u = v.u;
  u += 0x7fffu + ((u >> 16) & 1u);   // RNE
  return (ushort)(u >> 16);
}
__device__ __forceinline__ ushort f2h(float f) {
  _Float16 h = (_Float16)f;
  union { _Float16 h; ushort u; } v; v.h = h;
  return v.u;
}

// ---------------- cast fp32 -> bf16 ----------------
__global__ void cast_bf16_kernel(const float* __restrict__ in, ushort* __restrict__ out, int n4) {
  int i = blockIdx.x * 256 + threadIdx.x;
  if (i >= n4) return;
  float4 v = ((const float4*)in)[i];
  ushort4 o;
  o.x = f2bf(v.x); o.y = f2bf(v.y); o.z = f2bf(v.z); o.w = f2bf(v.w);
  ((ushort4*)out)[i] = o;
}

// ---------------- 256x256 8-phase bt-GEMM ----------------
// out[m][n] = sum_k A[m][k]*B[n][k] + bias[n]
// MODE 0: out bf16 at [(b*16+h)*2048+t][dd]  (Q/K layout)
// MODE 1: out fp16 at [(b*16+h)*128+dd][t]   (V transposed)
// MODE 2: out fp32 row-major [m][n]
//
// Structure: BM=BN=256, BK=64, 512 threads (2x4 waves), per-wave 128x64 out.
// LDS 128KB: A/B double-buffered 256x64 bf16 tiles, chunk-swizzled (ck ^= row&7).
// 8 phases per iteration (2 K-tiles); counted vmcnt(4) at phases 4/8 only.
#define DS_A(buf, mi_, kk_) (*(const bf16x8*)&As[buf][(wm + (mi_) * 16 + l15) * 64 + ckoff[kk_]])
#define DS_B(buf, ni_, kk_) (*(const bf16x8*)&Bs[buf][(wn + (ni_) * 16 + l15) * 64 + ckoff[kk_]])

#define PHASE(buf, p, STAGES, ENDW) {                                          \
    bf16x8 af[2][2];                                                           \
    if ((p) == 0) {                                                            \
      _Pragma("unroll") for (int ni = 0; ni < 4; ++ni)                         \
        _Pragma("unroll") for (int kk = 0; kk < 2; ++kk)                       \
          bfr[ni][kk] = DS_B(buf, ni, kk);                                     \
    }                                                                          \
    _Pragma("unroll") for (int mi2 = 0; mi2 < 2; ++mi2)                        \
      _Pragma("unroll") for (int kk = 0; kk < 2; ++kk)                         \
        af[mi2][kk] = DS_A(buf, 2 * (p) + mi2, kk);                            \
    STAGES                                                                     \
    __builtin_amdgcn_s_barrier();                                              \
    asm volatile("s_waitcnt lgkmcnt(0)" ::: "memory");                         \
    __builtin_amdgcn_s_setprio(1);                                             \
    _Pragma("unroll") for (int mi2 = 0; mi2 < 2; ++mi2)                        \
      _Pragma("unroll") for (int ni = 0; ni < 4; ++ni)                         \
        _Pragma("unroll") for (int kk = 0; kk < 2; ++kk)                       \
          acc[2 * (p) + mi2][ni] = __builtin_amdgcn_mfma_f32_16x16x32_bf16(    \
              af[mi2][kk], bfr[ni][kk], acc[2 * (p) + mi2][ni], 0, 0, 0);      \
    __builtin_amdgcn_s_setprio(0);                                             \
    ENDW                                                                       \
    __builtin_amdgcn_s_barrier();                                              \
  }

template <int MODE>
__global__ __launch_bounds__(512, 2)
void gemm256(const ushort* __restrict__ A, const ushort* __restrict__ Bm,
             const float* __restrict__ bias, void* __restrict__ outp,
             int M, int N, int K) {
  __shared__ ushort As[2][16384];   // [buf][256 rows x 64 k], swizzled chunks
  __shared__ ushort Bs[2][16384];
  const int tid  = threadIdx.x;
  const int wave = tid >> 6, lane = tid & 63;
  const int l15  = lane & 15, quad = lane >> 4;

  // bijective XCD swizzle (nwg = 256 divisible by 8): XCD x gets a 4x8 tile region
  const int nwg = gridDim.x;
  const int cpx = nwg >> 3;
  const int swz = (blockIdx.x & 7) * cpx + (blockIdx.x >> 3);
  const int nbn = N >> 8;
  const int m0 = (swz / nbn) * 256;
  const int n0 = (swz % nbn) * 256;

  const int wm = (wave >> 2) << 7;    // 0 or 128
  const int wn = (wave & 3) << 6;     // 0,64,128,192
  const int sx = l15 & 7;
  const int ckoff[2] = { (quad ^ sx) * 8, ((4 + quad) ^ sx) * 8 };

  const ushort* Ag = A  + (size_t)m0 * K;
  const ushort* Bg = Bm + (size_t)n0 * K;

  // stage one half-tile (128 rows x 64 k = 16KB): linear LDS dest, inverse-swizzled
  // global source (global_load_lds writes base+lane*16 only)
  auto stage = [&](const ushort* src, ushort* dst, int h, int kt) {
#pragma unroll
    for (int i = 0; i < 2; ++i) {
      int c = i * 512 + tid;
      int row = c >> 3, ckL = c & 7;
      const ushort* g = src + (size_t)(h * 128 + row) * K + kt * 64 + (ckL ^ (row & 7)) * 8;
      __builtin_amdgcn_global_load_lds((G1 uint*)g, (L3 uint*)(dst + h * 8192 + c * 8), 16, 0, 0);
    }
  };

  f32x4 acc[8][4] = {};

  // prologue: tile0 -> buf0 (B then A), tile1 B -> buf1 ; leave B(buf1) in flight
  stage(Bg, &Bs[0][0], 0, 0);
  stage(Bg, &Bs[0][0], 1, 0);
  stage(Ag, &As[0][0], 0, 0);
  stage(Ag, &As[0][0], 1, 0);
  stage(Bg, &Bs[1][0], 0, 1);
  stage(Bg, &Bs[1][0], 1, 1);
  asm volatile("s_waitcnt vmcnt(4)" ::: "memory");
  __builtin_amdgcn_s_barrier();

  const int NKT = K >> 6;               // 32 K-tiles
  for (int j = 0; j < (NKT >> 1); ++j) {
    const int t1 = 2 * j + 1;
    const int t2 = (2 * j + 2) & (NKT - 1);   // wrap on last iter (staged, never read)
    const int t3 = (2 * j + 3) & (NKT - 1);
    bf16x8 bfr[4][2];
    // phases 1-4: compute buf0 (tile 2j); stage A(buf1)<-t1, B(buf0)<-t2
    PHASE(0, 0, stage(Ag, &As[1][0], 0, t1);, )
    PHASE(0, 1, stage(Ag, &As[1][0], 1, t1); stage(Bg, &Bs[0][0], 0, t2);, )
    PHASE(0, 2, stage(Bg, &Bs[0][0], 1, t2);, )
    PHASE(0, 3, , asm volatile("s_waitcnt vmcnt(4)" ::: "memory");)
    // phases 5-8: compute buf1 (tile 2j+1); stage A(buf0)<-t2, B(buf1)<-t3
    PHASE(1, 0, stage(Ag, &As[0][0], 0, t2);, )
    PHASE(1, 1, stage(Ag, &As[0][0], 1, t2);, )
    PHASE(1, 2, stage(Bg, &Bs[1][0], 0, t3);, )
    PHASE(1, 3, stage(Bg, &Bs[1][0], 1, t3);, asm volatile("s_waitcnt vmcnt(4)" ::: "memory");)
  }
  // drain: pending LDS-DMA must not outlive the block
  asm volatile("s_waitcnt vmcnt(0)" ::: "memory");

  // epilogue: m = m0+wm+mi*16+quad*4+r, n = n0+wn+ni*16+l15 (C/D: row=quad*4+r, col=l15)
#pragma unroll
  for (int mi = 0; mi < 8; ++mi)
#pragma unroll
    for (int ni = 0; ni < 4; ++ni) {
      int n = n0 + wn + ni * 16 + l15;
      float bv = bias[n];
      int mbase = m0 + wm + mi * 16 + quad * 4;
      if (MODE == 1) {
        int b = mbase >> 11, t = mbase & 2047;
        int h = n >> 7, dd = n & 127;
        ushort4 o;
        o.x = f2h(acc[mi][ni][0] + bv);
        o.y = f2h(acc[mi][ni][1] + bv);
        o.z = f2h(acc[mi][ni][2] + bv);
        o.w = f2h(acc[mi][ni][3] + bv);
        *(ushort4*)&((ushort*)outp)[(((size_t)(b * 16 + h) * 128 + dd) << 11) + t] = o;
      } else {
#pragma unroll
        for (int r = 0; r < 4; ++r) {
          int m = mbase + r;
          float v = acc[mi][ni][r] + bv;
          if (MODE == 0) {
            int b = m >> 11, t = m & 2047, h = n >> 7, dd = n & 127;
            ((ushort*)outp)[(((size_t)(b * 16 + h) * 2048 + t) << 7) + dd] = f2bf(v);
          } else {
            ((float*)outp)[(size_t)m * N + n] = v;
          }
        }
      }
    }
}

// ---------------- flash attention (S^T form) ----------------
// Q,K: (bh,t,d) bf16.  Vt: (bh,d,t) fp16.  Y: (b,t,C) bf16.
// S^T = K.Q^T via 16x16x32 bf16 (A=K, B=Q): C-layout lane=qr(l15), reg=kc(quad*4+r)
// -> directly the B-frag of 16x16x16 f16 PV (no LDS round-trip for P).
// O kept transposed (OT[dd][qr]) so per-row softmax state is lane-uniform.
__global__ __launch_bounds__(256, 3)
void attn_kernel(const ushort* __restrict__ Q, const ushort* __restrict__ Kh,
                 const ushort* __restrict__ Vt, const float* __restrict__ mask,
                 ushort* __restrict__ Y) {
  __shared__ ushort Ks[64 * 128];   // XOR-swizzled: chunk(t,ck) at t*16 + (ck^ (t&15))
  __shared__ ushort Vs[128 * 64];   // XOR-swizzled: chunk(d,ck) at d*8  + (ck^ (d&7))
  const int tid  = threadIdx.x;
  const int wave = tid >> 6, lane = tid & 63;
  const int l15  = lane & 15, quad = lane >> 4;
  const int bh = blockIdx.x;                  // bh-major
  const int qt = 15 - blockIdx.y;             // longest blocks dispatch first
  const int b  = bh >> 4, h = bh & 15;
  const int qw0 = qt * 128 + wave * 32;
  const ushort* Qb = Q  + (size_t)bh * 2048 * 128;
  const ushort* Kb = Kh + (size_t)bh * 2048 * 128;
  const ushort* Vb = Vt + (size_t)bh * 128 * 2048;
  const float*  mrow = mask + b * 2048;

  // Q B-frags (persistent): lane l15 = qr, k=d = dk*32+quad*8..+7
  bf16x8 aq[2][4];
#pragma unroll
  for (int q2 = 0; q2 < 2; ++q2)
#pragma unroll
    for (int dk = 0; dk < 4; ++dk)
      aq[q2][dk] = *(const bf16x8*)(Qb + (size_t)(qw0 + q2 * 16 + l15) * 128 + dk * 32 + quad * 8);

  float mi_[2], li[2];
  f32x4 OT[8][2] = {};   // OT[ddt][q2]: rows dd=ddt*16+quad*4+r, cols qr=q2*16+l15
  mi_[0] = mi_[1] = -3.0e38f;
  li[0] = li[1] = 0.f;

  const float scale = 0.08838834764831845f;  // 1/sqrt(128)
  const int nkt = 2 * qt + 2;
  for (int it = 0; it < nkt; ++it) {
    const int k0 = it * 64;
    __syncthreads();
    // stage K tile (64 t x 128 d, 16KB) swizzled
#pragma unroll
    for (int i = 0; i < 4; ++i) {
      int c = i * 256 + tid;                      // LDS chunk 0..1023
      int t = c >> 4, ckG = (c & 15) ^ (t & 15);  // global chunk for this LDS slot
      __builtin_amdgcn_global_load_lds((G1 uint*)(Kb + (size_t)(k0 + t) * 128 + ckG * 8),
                                       (L3 uint*)&Ks[c * 8], 16, 0, 0);
    }
    // stage V tile (128 d x 64 t, 16KB) swizzled
#pragma unroll
    for (int i = 0; i < 4; ++i) {
      int c = i * 256 + tid;
      int d = c >> 3, ckG = (c & 7) ^ (d & 7);
      __builtin_amdgcn_global_load_lds((G1 uint*)(Vb + (size_t)d * 2048 + k0 + ckG * 8),
                                       (L3 uint*)&Vs[c * 8], 16, 0, 0);
    }
    __syncthreads();

    if (k0 <= qw0 + 31) {    // tile intersects this wave's causal range
      float4 mk[4];
#pragma unroll
      for (int ns = 0; ns < 4; ++ns)
        mk[ns] = *(const float4*)&mrow[k0 + ns * 16 + quad * 4];

      // S^T: A = K (lane l15 = kc-row), B = Q
      f32x4 s[2][4] = {};
#pragma unroll
      for (int ns = 0; ns < 4; ++ns) {
        bf16x8 kb[4];
#pragma unroll
        for (int dk = 0; dk < 4; ++dk) {
          int ck = ((dk * 4 + quad) ^ l15);   // swizzled chunk
          kb[dk] = *(const bf16x8*)&Ks[(ns * 16 + l15) * 128 + ck * 8];
        }
#pragma unroll
        for (int q2 = 0; q2 < 2; ++q2)
#pragma unroll
          for (int dk = 0; dk < 4; ++dk)
            s[q2][ns] = __builtin_amdgcn_mfma_f32_16x16x32_bf16(kb[dk], aq[q2][dk], s[q2][ns], 0, 0, 0);
      }

      // scale + additive mask + causal (element: kc = k0+16ns+quad*4+r, qr = qw0+q2*16+l15)
      half4 pf[2][4];
#pragma unroll
      for (int q2 = 0; q2 < 2; ++q2) {
        const int qr = qw0 + q2 * 16 + l15;
#pragma unroll
        for (int ns = 0; ns < 4; ++ns)
#pragma unroll
          for (int r = 0; r < 4; ++r) {
            int kc = k0 + ns * 16 + quad * 4 + r;
            float v = s[q2][ns][r] * scale + mk[ns][r];
            s[q2][ns][r] = (kc > qr) ? -3.0e38f : v;
          }
        // row softmax: state lives in every lane (4 quad-copies, identical)
        float rm = -3.0e38f;
#pragma unroll
        for (int ns = 0; ns < 4; ++ns)
          rm = fmaxf(rm, fmaxf(fmaxf(s[q2][ns][0], s[q2][ns][1]), fmaxf(s[q2][ns][2], s[q2][ns][3])));
        rm = fmaxf(rm, __shfl_xor(rm, 16));
        rm = fmaxf(rm, __shfl_xor(rm, 32));
        float mnew = fmaxf(mi_[q2], rm);
        float al = __expf(mi_[q2] - mnew);
        float rs = 0.f;
#pragma unroll
        for (int ns = 0; ns < 4; ++ns) {
#pragma unroll
          for (int r = 0; r < 4; ++r) {
            float p = __expf(s[q2][ns][r] - mnew);
            s[q2][ns][r] = p;
            rs += p;
          }
          pf[q2][ns] = half4{(_Float16)s[q2][ns][0], (_Float16)s[q2][ns][1],
                             (_Float16)s[q2][ns][2], (_Float16)s[q2][ns][3]};
        }
        rs += __shfl_xor(rs, 16);
        rs += __shfl_xor(rs, 32);
        li[q2] = li[q2] * al + rs;
        mi_[q2] = mnew;
#pragma unroll
        for (int ddt = 0; ddt < 8; ++ddt) OT[ddt][q2] *= al;
      }

      // PV: OT[ddt][q2] += mfma_16x16x16_f16(A=V^T frag, B=P frag)
#pragma unroll
      for (int ns = 0; ns < 4; ++ns)
#pragma unroll
        for (int ddt = 0; ddt < 8; ++ddt) {
          int row = ddt * 16 + l15;
          int ck = (2 * ns + (quad >> 1)) ^ (l15 & 7);   // swizzled 16B chunk
          half4 vf = *(const half4*)&Vs[row * 64 + ck * 8 + (quad & 1) * 4];
#pragma unroll
          for (int q2 = 0; q2 < 2; ++q2)
            OT[ddt][q2] = __builtin_amdgcn_mfma_f32_16x16x16f16(vf, pf[q2][ns], OT[ddt][q2], 0, 0, 0);
        }
    }
  }

  // epilogue: O[qr][dd] = OT[dd][qr] / li ; write 8B per (ddt,q2) per lane
#pragma unroll
  for (int q2 = 0; q2 < 2; ++q2) {
    float inv = 1.0f / li[q2];
    int t = qw0 + q2 * 16 + l15;
#pragma unroll
    for (int ddt = 0; ddt < 8; ++ddt) {
      ushort4 o;
      o.x = f2bf(OT[ddt][q2][0] * inv);
      o.y = f2bf(OT[ddt][q2][1] * inv);
      o.z = f2bf(OT[ddt][q2][2] * inv);
      o.w = f2bf(OT[ddt][q2][3] * inv);
      *(ushort4*)&Y[((size_t)(b * 2048 + t)) * 2048 + h * 128 + ddt * 16 + quad * 4] = o;
    }
  }
}

extern "C" void kernel_launch(void* const* d_in, const int* in_sizes, int n_in,
                              void* d_out, int out_size, void* d_ws, size_t ws_size,
                              hipStream_t stream) {
  const float* x     = (const float*)d_in[0];
  const float* amask = (const float*)d_in[1];
  const float* Wq = (const float*)d_in[2];
  const float* bq = (const float*)d_in[3];
  const float* Wk = (const float*)d_in[4];
  const float* bk = (const float*)d_in[5];
  const float* Wv = (const float*)d_in[6];
  const float* bv = (const float*)d_in[7];
  const float* Wp = (const float*)d_in[8];
  const float* bp = (const float*)d_in[9];

  char* ws = (char*)d_ws;
  ushort* xb  = (ushort*)(ws);                  // 8192x2048 bf16 = 32MB
  ushort* Wqb = (ushort*)(ws + 33554432);       // 8MB each
  ushort* Wkb = (ushort*)(ws + 41943040);
  ushort* Wvb = (ushort*)(ws + 50331648);
  ushort* Wpb = (ushort*)(ws + 58720256);
  ushort* Qb  = (ushort*)(ws + 67108864);       // (bh,t,d) bf16 32MB
  ushort* Kb  = (ushort*)(ws + 100663296);      // (bh,t,d) bf16 32MB
  ushort* Vtb = (ushort*)(ws + 134217728);      // (bh,d,t) fp16 32MB
  ushort* Yb  = (ushort*)(ws + 167772160);      // (b*t, C) bf16 32MB

  cast_bf16_kernel<<<16384, 256, 0, stream>>>(x,  xb,  4194304);
  cast_bf16_kernel<<<4096,  256, 0, stream>>>(Wq, Wqb, 1048576);
  cast_bf16_kernel<<<4096,  256, 0, stream>>>(Wk, Wkb, 1048576);
  cast_bf16_kernel<<<4096,  256, 0, stream>>>(Wv, Wvb, 1048576);
  cast_bf16_kernel<<<4096,  256, 0, stream>>>(Wp, Wpb, 1048576);

  // (M/256)*(N/256) = 32*8 = 256 blocks, 1 per CU
  gemm256<0><<<256, 512, 0, stream>>>(xb, Wqb, bq, Qb,  8192, 2048, 2048);
  gemm256<0><<<256, 512, 0, stream>>>(xb, Wkb, bk, Kb,  8192, 2048, 2048);
  gemm256<1><<<256, 512, 0, stream>>>(xb, Wvb, bv, Vtb, 8192, 2048, 2048);

  attn_kernel<<<dim3(64, 16), 256, 0, stream>>>(Qb, Kb, Vtb, amask, Yb);

  gemm256<2><<<256, 512, 0, stream>>>(Yb, Wpb, bp, d_out, 8192, 2048, 2048);
}

// Round 2
// 550.113 us; speedup vs baseline: 1.2595x; 1.1643x over previous
//
#include <hip/hip_runtime.h>
#include <hip/hip_bf16.h>

#define G1 __attribute__((address_space(1)))
#define L3 __attribute__((address_space(3)))

typedef __bf16 bf16x8 __attribute__((ext_vector_type(8)));
typedef _Float16 half4 __attribute__((ext_vector_type(4)));
typedef float f32x4 __attribute__((ext_vector_type(4)));

__device__ __forceinline__ ushort f2bf(float f) {
  union { float f; uint u; } v; v.f = f;
  uint u = v.u;
  u += 0x7fffu + ((u >> 16) & 1u);   // RNE
  return (ushort)(u >> 16);
}
__device__ __forceinline__ ushort f2h(float f) {
  _Float16 h = (_Float16)f;
  union { _Float16 h; ushort u; } v; v.h = h;
  return v.u;
}

// ---------------- cast fp32 -> bf16 ----------------
__global__ void cast_bf16_kernel(const float* __restrict__ in, ushort* __restrict__ out, int n4) {
  int i = blockIdx.x * 256 + threadIdx.x;
  if (i >= n4) return;
  float4 v = ((const float4*)in)[i];
  ushort4 o;
  o.x = f2bf(v.x); o.y = f2bf(v.y); o.z = f2bf(v.z); o.w = f2bf(v.w);
  ((ushort4*)out)[i] = o;
}

// ---------------- 256x256 bt-GEMM, BK=32 ring-of-4 pipeline ----------------
// out[m][n] = sum_k A[m][k]*B[n][k] + bias[n]
// MODE 0: out bf16 at [(b*16+h)*2048+t][dd]  (Q/K layout)
// MODE 1: out fp16 at [(b*16+h)*128+dd][t]   (V transposed)
// MODE 2: out fp32 row-major [m][n]
//
// BM=BN=256, BK=32, 512 threads (2x4 waves), per-wave 128x64 out.
// LDS 128KB: 4-deep ring of (A,B) 256x32 bf16 tiles, chunk-swizzled ck ^= (row>>1)&3.
// Per tile: 2 phases x 16 MFMA; 1 half-tile staged per phase (tile t+3);
// one vmcnt(8) drain per tile. Invariant after tile t's drain: outstanding =
// {A(t+2),B(t+2),A(t+3),B(t+3)} (8 loads) and tile t+1 fully landed.
#define STAGE_A(bf, kt) {                                                       \
    __builtin_amdgcn_global_load_lds((G1 uint*)(Ag0 + (kt) * 32),               \
        (L3 uint*)&As[bf][tid * 8], 16, 0, 0);                                  \
    __builtin_amdgcn_global_load_lds((G1 uint*)(Ag1 + (kt) * 32),               \
        (L3 uint*)&As[bf][4096 + tid * 8], 16, 0, 0);                           \
  }
#define STAGE_B(bf, kt) {                                                       \
    __builtin_amdgcn_global_load_lds((G1 uint*)(Bg0 + (kt) * 32),               \
        (L3 uint*)&Bs[bf][tid * 8], 16, 0, 0);                                  \
    __builtin_amdgcn_global_load_lds((G1 uint*)(Bg1 + (kt) * 32),               \
        (L3 uint*)&Bs[bf][4096 + tid * 8], 16, 0, 0);                           \
  }

template <int MODE>
__global__ __launch_bounds__(512, 2)
void gemm256(const ushort* __restrict__ A, const ushort* __restrict__ Bm,
             const float* __restrict__ bias, void* __restrict__ outp,
             int M, int N, int K) {
  __shared__ ushort As[4][8192];   // [buf][256 rows x 32 k] = 16KB each
  __shared__ ushort Bs[4][8192];
  const int tid  = threadIdx.x;
  const int wave = tid >> 6, lane = tid & 63;
  const int l15  = lane & 15, quad = lane >> 4;

  // bijective XCD swizzle (nwg = 256, divisible by 8): XCD x gets a 4x8 region
  const int nwg = gridDim.x;
  const int cpx = nwg >> 3;
  const int swz = (blockIdx.x & 7) * cpx + (blockIdx.x >> 3);
  const int nbn = N >> 8;
  const int m0 = (swz / nbn) * 256;
  const int n0 = (swz % nbn) * 256;

  const int wm = (wave >> 2) << 7;    // 0 or 128
  const int wn = (wave & 3) << 6;     // 0,64,128,192

  // fragment read offset: row*32 + (quad ^ ((row>>1)&3))*8 ; row = base16 + l15
  // -> swizzle term is (l15>>1)&3, a per-thread constant. Bank-uniform (8/bank).
  const int fck = (quad ^ ((l15 >> 1) & 3)) << 3;

  // stage addressing: chunk c = h*512 + tid ; row = c>>2, ckL = c&3;
  // LDS slot ckL holds global chunk ckL ^ ((row>>1)&3)  (same involution as read)
  const int srow = tid >> 2;
  const int sck  = ((tid & 3) ^ ((srow >> 1) & 3)) * 8;
  const ushort* Ag0 = A  + (size_t)(m0 + srow) * K + sck;
  const ushort* Ag1 = A  + (size_t)(m0 + 128 + srow) * K + sck;
  const ushort* Bg0 = Bm + (size_t)(n0 + srow) * K + sck;
  const ushort* Bg1 = Bm + (size_t)(n0 + 128 + srow) * K + sck;

  f32x4 acc[8][4] = {};

  // prologue: stage tiles 0,1,2 (12 loads); vmcnt(8) -> tile 0 landed
  STAGE_A(0, 0) STAGE_B(0, 0)
  STAGE_A(1, 1) STAGE_B(1, 1)
  STAGE_A(2, 2) STAGE_B(2, 2)
  asm volatile("s_waitcnt vmcnt(8)" ::: "memory");
  __builtin_amdgcn_s_barrier();

  const int NT = K >> 5;               // 64 K-tiles
  for (int j = 0; j < NT; j += 4) {
#pragma unroll
    for (int tt = 0; tt < 4; ++tt) {
      const int t   = j + tt;
      const int kt3 = (t + 3) & (NT - 1);   // wrap: staged but never read
      const int b3  = (tt + 3) & 3;
      bf16x8 bfr[4], af[4];
      // ---- phase 0: frags (mi 0-3 + all B) ; stage A(t+3) ----
#pragma unroll
      for (int ni = 0; ni < 4; ++ni)
        bfr[ni] = *(const bf16x8*)&Bs[tt][(wn + ni * 16 + l15) * 32 + fck];
#pragma unroll
      for (int mi = 0; mi < 4; ++mi)
        af[mi] = *(const bf16x8*)&As[tt][(wm + mi * 16 + l15) * 32 + fck];
      STAGE_A(b3, kt3)
      __builtin_amdgcn_s_barrier();
      asm volatile("s_waitcnt lgkmcnt(0)" ::: "memory");
      __builtin_amdgcn_s_setprio(1);
#pragma unroll
      for (int mi = 0; mi < 4; ++mi)
#pragma unroll
        for (int ni = 0; ni < 4; ++ni)
          acc[mi][ni] = __builtin_amdgcn_mfma_f32_16x16x32_bf16(af[mi], bfr[ni], acc[mi][ni], 0, 0, 0);
      __builtin_amdgcn_s_setprio(0);
      __builtin_amdgcn_s_barrier();
      // ---- phase 1: frags (mi 4-7) ; stage B(t+3) ; drain ----
#pragma unroll
      for (int mi = 0; mi < 4; ++mi)
        af[mi] = *(const bf16x8*)&As[tt][(wm + (mi + 4) * 16 + l15) * 32 + fck];
      STAGE_B(b3, kt3)
      __builtin_amdgcn_s_barrier();
      asm volatile("s_waitcnt lgkmcnt(0)" ::: "memory");
      __builtin_amdgcn_s_setprio(1);
#pragma unroll
      for (int mi = 0; mi < 4; ++mi)
#pragma unroll
        for (int ni = 0; ni < 4; ++ni)
          acc[mi + 4][ni] = __builtin_amdgcn_mfma_f32_16x16x32_bf16(af[mi], bfr[ni], acc[mi + 4][ni], 0, 0, 0);
      __builtin_amdgcn_s_setprio(0);
      asm volatile("s_waitcnt vmcnt(8)" ::: "memory");
      __builtin_amdgcn_s_barrier();
    }
  }
  // pending LDS-DMA must not outlive the block
  asm volatile("s_waitcnt vmcnt(0)" ::: "memory");

  // epilogue: m = m0+wm+mi*16+quad*4+r, n = n0+wn+ni*16+l15 (C/D: row=quad*4+r, col=l15)
#pragma unroll
  for (int mi = 0; mi < 8; ++mi)
#pragma unroll
    for (int ni = 0; ni < 4; ++ni) {
      int n = n0 + wn + ni * 16 + l15;
      float bv = bias[n];
      int mbase = m0 + wm + mi * 16 + quad * 4;
      if (MODE == 1) {
        int b = mbase >> 11, t = mbase & 2047;
        int h = n >> 7, dd = n & 127;
        ushort4 o;
        o.x = f2h(acc[mi][ni][0] + bv);
        o.y = f2h(acc[mi][ni][1] + bv);
        o.z = f2h(acc[mi][ni][2] + bv);
        o.w = f2h(acc[mi][ni][3] + bv);
        *(ushort4*)&((ushort*)outp)[(((size_t)(b * 16 + h) * 128 + dd) << 11) + t] = o;
      } else {
#pragma unroll
        for (int r = 0; r < 4; ++r) {
          int m = mbase + r;
          float v = acc[mi][ni][r] + bv;
          if (MODE == 0) {
            int b = m >> 11, t = m & 2047, h = n >> 7, dd = n & 127;
            ((ushort*)outp)[(((size_t)(b * 16 + h) * 2048 + t) << 7) + dd] = f2bf(v);
          } else {
            ((float*)outp)[(size_t)m * N + n] = v;
          }
        }
      }
    }
}

// ---------------- flash attention (S^T form), double-buffered K/V ----------------
// Q,K: (bh,t,d) bf16.  Vt: (bh,d,t) fp16.  Y: (b,t,C) bf16.
// S^T = K.Q^T via 16x16x32 bf16 (A=K, B=Q): C-layout lane=qr(l15), reg=kc(quad*4+r)
// -> directly the B-frag of 16x16x16 f16 PV (no LDS round-trip for P).
// O kept transposed (OT[dd][qr]) so per-row softmax state is lane-uniform.
// Pipeline: stage tile it+1 right after top barrier; wait for it only at the
// next iteration's top (vmcnt(0)+barrier) -> full tile of compute covers latency.
__global__ __launch_bounds__(256, 2)
void attn_kernel(const ushort* __restrict__ Q, const ushort* __restrict__ Kh,
                 const ushort* __restrict__ Vt, const float* __restrict__ mask,
                 ushort* __restrict__ Y) {
  __shared__ ushort Ks[2][64 * 128];   // XOR-swizzled: chunk(t,ck) at t*16 + (ck^(t&15))
  __shared__ ushort Vs[2][128 * 64];   // XOR-swizzled: chunk(d,ck) at d*8  + (ck^(d&7))
  const int tid  = threadIdx.x;
  const int wave = tid >> 6, lane = tid & 63;
  const int l15  = lane & 15, quad = lane >> 4;
  const int bh = blockIdx.x;                  // bh-major
  const int qt = 15 - blockIdx.y;             // longest blocks dispatch first
  const int b  = bh >> 4, h = bh & 15;
  const int qw0 = qt * 128 + wave * 32;
  const ushort* Qb = Q  + (size_t)bh * 2048 * 128;
  const ushort* Kb = Kh + (size_t)bh * 2048 * 128;
  const ushort* Vb = Vt + (size_t)bh * 128 * 2048;
  const float*  mrow = mask + b * 2048;

  // Q B-frags (persistent): lane l15 = qr, k=d = dk*32+quad*8..+7
  bf16x8 aq[2][4];
#pragma unroll
  for (int q2 = 0; q2 < 2; ++q2)
#pragma unroll
    for (int dk = 0; dk < 4; ++dk)
      aq[q2][dk] = *(const bf16x8*)(Qb + (size_t)(qw0 + q2 * 16 + l15) * 128 + dk * 32 + quad * 8);

  auto stageKV = [&](int it, int bufb) {
    const int k0s = it * 64;
#pragma unroll
    for (int i = 0; i < 4; ++i) {
      int c = i * 256 + tid;                      // LDS chunk 0..1023
      int t = c >> 4, ckG = (c & 15) ^ (t & 15);  // global chunk for this LDS slot
      __builtin_amdgcn_global_load_lds((G1 uint*)(Kb + (size_t)(k0s + t) * 128 + ckG * 8),
                                       (L3 uint*)&Ks[bufb][c * 8], 16, 0, 0);
    }
#pragma unroll
    for (int i = 0; i < 4; ++i) {
      int c = i * 256 + tid;
      int d = c >> 3, ckG = (c & 7) ^ (d & 7);
      __builtin_amdgcn_global_load_lds((G1 uint*)(Vb + (size_t)d * 2048 + k0s + ckG * 8),
                                       (L3 uint*)&Vs[bufb][c * 8], 16, 0, 0);
    }
  };

  float mi_[2], li[2];
  f32x4 OT[8][2] = {};   // OT[ddt][q2]: rows dd=ddt*16+quad*4+r, cols qr=q2*16+l15
  mi_[0] = mi_[1] = -3.0e38f;
  li[0] = li[1] = 0.f;

  const float scale = 0.08838834764831845f;  // 1/sqrt(128)
  const int nkt = 2 * qt + 2;

  stageKV(0, 0);   // prologue
  for (int it = 0; it < nkt; ++it) {
    const int k0 = it * 64;
    const int bb = it & 1;
    asm volatile("s_waitcnt vmcnt(0)" ::: "memory");   // tile it landed (this wave)
    __builtin_amdgcn_s_barrier();                      // ... for all waves
    if (it + 1 < nkt) stageKV(it + 1, bb ^ 1);         // in flight across compute

    if (k0 <= qw0 + 31) {    // tile intersects this wave's causal range
      float4 mk[4];
#pragma unroll
      for (int ns = 0; ns < 4; ++ns)
        mk[ns] = *(const float4*)&mrow[k0 + ns * 16 + quad * 4];

      // S^T: A = K (lane l15 = kc-row), B = Q
      f32x4 s[2][4] = {};
#pragma unroll
      for (int ns = 0; ns < 4; ++ns) {
        bf16x8 kb[4];
#pragma unroll
        for (int dk = 0; dk < 4; ++dk) {
          int ck = ((dk * 4 + quad) ^ l15);   // swizzled chunk
          kb[dk] = *(const bf16x8*)&Ks[bb][(ns * 16 + l15) * 128 + ck * 8];
        }
#pragma unroll
        for (int q2 = 0; q2 < 2; ++q2)
#pragma unroll
          for (int dk = 0; dk < 4; ++dk)
            s[q2][ns] = __builtin_amdgcn_mfma_f32_16x16x32_bf16(kb[dk], aq[q2][dk], s[q2][ns], 0, 0, 0);
      }

      // scale + additive mask + causal (element: kc = k0+16ns+quad*4+r, qr = qw0+q2*16+l15)
      half4 pf[2][4];
#pragma unroll
      for (int q2 = 0; q2 < 2; ++q2) {
        const int qr = qw0 + q2 * 16 + l15;
#pragma unroll
        for (int ns = 0; ns < 4; ++ns)
#pragma unroll
          for (int r = 0; r < 4; ++r) {
            int kc = k0 + ns * 16 + quad * 4 + r;
            float v = s[q2][ns][r] * scale + mk[ns][r];
            s[q2][ns][r] = (kc > qr) ? -3.0e38f : v;
          }
        // row softmax: state lives in every lane (4 quad-copies, identical)
        float rm = -3.0e38f;
#pragma unroll
        for (int ns = 0; ns < 4; ++ns)
          rm = fmaxf(rm, fmaxf(fmaxf(s[q2][ns][0], s[q2][ns][1]), fmaxf(s[q2][ns][2], s[q2][ns][3])));
        rm = fmaxf(rm, __shfl_xor(rm, 16));
        rm = fmaxf(rm, __shfl_xor(rm, 32));
        float mnew = fmaxf(mi_[q2], rm);
        float al = __expf(mi_[q2] - mnew);
        float rs = 0.f;
#pragma unroll
        for (int ns = 0; ns < 4; ++ns) {
#pragma unroll
          for (int r = 0; r < 4; ++r) {
            float p = __expf(s[q2][ns][r] - mnew);
            s[q2][ns][r] = p;
            rs += p;
          }
          pf[q2][ns] = half4{(_Float16)s[q2][ns][0], (_Float16)s[q2][ns][1],
                             (_Float16)s[q2][ns][2], (_Float16)s[q2][ns][3]};
        }
        rs += __shfl_xor(rs, 16);
        rs += __shfl_xor(rs, 32);
        li[q2] = li[q2] * al + rs;
        mi_[q2] = mnew;
#pragma unroll
        for (int ddt = 0; ddt < 8; ++ddt) OT[ddt][q2] *= al;
      }

      // PV: OT[ddt][q2] += mfma_16x16x16_f16(A=V^T frag, B=P frag)
#pragma unroll
      for (int ns = 0; ns < 4; ++ns)
#pragma unroll
        for (int ddt = 0; ddt < 8; ++ddt) {
          int row = ddt * 16 + l15;
          int ck = (2 * ns + (quad >> 1)) ^ (l15 & 7);   // swizzled 16B chunk
          half4 vf = *(const half4*)&Vs[bb][row * 64 + ck * 8 + (quad & 1) * 4];
#pragma unroll
          for (int q2 = 0; q2 < 2; ++q2)
            OT[ddt][q2] = __builtin_amdgcn_mfma_f32_16x16x16f16(vf, pf[q2][ns], OT[ddt][q2], 0, 0, 0);
        }
    }
    __builtin_amdgcn_s_barrier();   // all reads of buf bb done before next stage to it
  }

  // epilogue: O[qr][dd] = OT[dd][qr] / li ; write 8B per (ddt,q2) per lane
#pragma unroll
  for (int q2 = 0; q2 < 2; ++q2) {
    float inv = 1.0f / li[q2];
    int t = qw0 + q2 * 16 + l15;
#pragma unroll
    for (int ddt = 0; ddt < 8; ++ddt) {
      ushort4 o;
      o.x = f2bf(OT[ddt][q2][0] * inv);
      o.y = f2bf(OT[ddt][q2][1] * inv);
      o.z = f2bf(OT[ddt][q2][2] * inv);
      o.w = f2bf(OT[ddt][q2][3] * inv);
      *(ushort4*)&Y[((size_t)(b * 2048 + t)) * 2048 + h * 128 + ddt * 16 + quad * 4] = o;
    }
  }
}

extern "C" void kernel_launch(void* const* d_in, const int* in_sizes, int n_in,
                              void* d_out, int out_size, void* d_ws, size_t ws_size,
                              hipStream_t stream) {
  const float* x     = (const float*)d_in[0];
  const float* amask = (const float*)d_in[1];
  const float* Wq = (const float*)d_in[2];
  const float* bq = (const float*)d_in[3];
  const float* Wk = (const float*)d_in[4];
  const float* bk = (const float*)d_in[5];
  const float* Wv = (const float*)d_in[6];
  const float* bv = (const float*)d_in[7];
  const float* Wp = (const float*)d_in[8];
  const float* bp = (const float*)d_in[9];

  char* ws = (char*)d_ws;
  ushort* xb  = (ushort*)(ws);                  // 8192x2048 bf16 = 32MB
  ushort* Wqb = (ushort*)(ws + 33554432);       // 8MB each
  ushort* Wkb = (ushort*)(ws + 41943040);
  ushort* Wvb = (ushort*)(ws + 50331648);
  ushort* Wpb = (ushort*)(ws + 58720256);
  ushort* Qb  = (ushort*)(ws + 67108864);       // (bh,t,d) bf16 32MB
  ushort* Kb  = (ushort*)(ws + 100663296);      // (bh,t,d) bf16 32MB
  ushort* Vtb = (ushort*)(ws + 134217728);      // (bh,d,t) fp16 32MB
  ushort* Yb  = (ushort*)(ws + 167772160);      // (b*t, C) bf16 32MB

  cast_bf16_kernel<<<16384, 256, 0, stream>>>(x,  xb,  4194304);
  cast_bf16_kernel<<<4096,  256, 0, stream>>>(Wq, Wqb, 1048576);
  cast_bf16_kernel<<<4096,  256, 0, stream>>>(Wk, Wkb, 1048576);
  cast_bf16_kernel<<<4096,  256, 0, stream>>>(Wv, Wvb, 1048576);
  cast_bf16_kernel<<<4096,  256, 0, stream>>>(Wp, Wpb, 1048576);

  // (M/256)*(N/256) = 32*8 = 256 blocks, 1 per CU
  gemm256<0><<<256, 512, 0, stream>>>(xb, Wqb, bq, Qb,  8192, 2048, 2048);
  gemm256<0><<<256, 512, 0, stream>>>(xb, Wkb, bk, Kb,  8192, 2048, 2048);
  gemm256<1><<<256, 512, 0, stream>>>(xb, Wvb, bv, Vtb, 8192, 2048, 2048);

  attn_kernel<<<dim3(64, 16), 256, 0, stream>>>(Qb, Kb, Vtb, amask, Yb);

  gemm256<2><<<256, 512, 0, stream>>>(Yb, Wpb, bp, d_out, 8192, 2048, 2048);
}